// Round 12
// baseline (269.924 us; speedup 1.0000x reference)
//
#include <hip/hip_runtime.h>

// GCN_77584289234976 — round 19.
// R18 post-mortem: apply-LDS-epilogue neutral; plateau at ~230 with mega2=75
// and ~156us in never-profiled serial stages (R16 proved stages serialize).
// R19: (a) Sexp merged INTO mega0 as a block range with INLINE LayerNorm
// (each Sexp block recomputes LN for its 128 rows from ne+te directly, ~2us;
// P/rs stay self-consistent) -> k_Sexp launch deleted, Sexp blocks overlap
// xtrans/poolt memory phases (m114). fp32 e buffer deleted.
// (b) aggr 2-phase double-buffer (T3 minimum recipe): STAGE(t+1)->buf^1
// issued BEFORE compute(t), one __syncthreads per iter -> stage HBM latency
// hides under 32-MFMA compute. LDS 64KB (aggr was 2 blk/CU anyway; gen
// co-residency 4->2/CU, acceptable: ~15us of gen work hides under aggr).
// MFMA 16x16x32 bf16 layout contract (m89/m97/m120):
//   a-frag: A[m][k], m=lane&15, k=(lane>>4)*8+j
//   b-frag: B[k][n], n=lane&15, k=(lane>>4)*8+j
//   d:      D[m][n], n(col)=lane&15, m(row)=(lane>>4)*4+reg

typedef unsigned short u16;
typedef unsigned int u32;
typedef __attribute__((ext_vector_type(8))) short bf16x8;
typedef __attribute__((ext_vector_type(4))) float f32x4;
typedef const __attribute__((address_space(1))) u16* gas1;
typedef __attribute__((address_space(3))) u16* las3;

#define NN 2048
#define EE 64
#define CC 128
#define BB 32

__device__ __forceinline__ u16 f2bf(float f) {
  u32 u = __builtin_bit_cast(u32, f);
  u += 0x7fffu + ((u >> 16) & 1u);   // round-to-nearest-even
  return (u16)(u >> 16);
}

__device__ __forceinline__ f32x4 mfma16(bf16x8 a, bf16x8 b, f32x4 c) {
  return __builtin_amdgcn_mfma_f32_16x16x32_bf16(a, b, c, 0, 0, 0);
}

// ---------------- mega0: sexp(1024) + xtrans(1024) + poolt(256) + prep(512)
__global__ __launch_bounds__(256) void k_mega0(
    const float* __restrict__ x, const float* __restrict__ ne,
    const float* __restrict__ te, const float* __restrict__ pool,
    const float* __restrict__ bias_pool, const float* __restrict__ lnw,
    const float* __restrict__ lnb,
    u16* __restrict__ e_bf, float* __restrict__ bias_out,
    u16* __restrict__ pool_r, u16* __restrict__ x_t, u16* __restrict__ xg_t,
    u16* __restrict__ P, float* __restrict__ rs) {
  __shared__ __align__(16) char smem[34816];
  int bid = blockIdx.x;
  int tid = threadIdx.x;
  if (bid < 1024) {
    // ---- sexp (inline LN): P = exp(e @ e^T) bf16 + atomic row sums.
    float* er = (float*)smem;             // [64][68]
    float* ec = (float*)(smem + 17408);   // [64][68]
    int n0 = (bid >> 5) * 64, m0 = (bid & 31) * 64;
    int nw = tid >> 6, d = tid & 63;
    float tev = te[d], lw = lnw[d], lb = lnb[d];
#pragma unroll 4
    for (int p = 0; p < 32; ++p) {
      int ri = p * 4 + nw;                // 0..127
      int n = ri < 64 ? n0 + ri : m0 + (ri - 64);
      float v = ne[n * EE + d] + tev;
      float s = v;
#pragma unroll
      for (int off = 32; off > 0; off >>= 1) s += __shfl_xor(s, off);
      float mean = s * (1.0f / 64.0f);
      float c = v - mean;
      float q = c * c;
#pragma unroll
      for (int off = 32; off > 0; off >>= 1) q += __shfl_xor(q, off);
      float inv = rsqrtf(q * (1.0f / 64.0f) + 1e-12f);
      float ev = c * inv * lw + lb;
      if (ri < 64) er[ri * 68 + d] = ev;
      else         ec[(ri - 64) * 68 + d] = ev;
    }
    __syncthreads();
    int tx = tid & 15, ty = tid >> 4;
    float acc[4][4] = {};
    for (int d4 = 0; d4 < 64; d4 += 4) {
      f32x4 av[4], bv[4];
#pragma unroll
      for (int i = 0; i < 4; ++i) av[i] = *(const f32x4*)&er[(ty + 16 * i) * 68 + d4];
#pragma unroll
      for (int j = 0; j < 4; ++j) bv[j] = *(const f32x4*)&ec[(tx + 16 * j) * 68 + d4];
#pragma unroll
      for (int i = 0; i < 4; ++i)
#pragma unroll
        for (int j = 0; j < 4; ++j) {
          acc[i][j] += av[i][0] * bv[j][0];
          acc[i][j] += av[i][1] * bv[j][1];
          acc[i][j] += av[i][2] * bv[j][2];
          acc[i][j] += av[i][3] * bv[j][3];
        }
    }
#pragma unroll
    for (int i = 0; i < 4; ++i) {
      float s = 0.f;
#pragma unroll
      for (int j = 0; j < 4; ++j) {
        float pv = __expf(acc[i][j]);
        P[(size_t)(n0 + ty + 16 * i) * NN + m0 + tx + 16 * j] = f2bf(pv);
        s += pv;
      }
#pragma unroll
      for (int off = 8; off > 0; off >>= 1) s += __shfl_xor(s, off);  // over tx
      if (tx == 0) atomicAdd(&rs[n0 + ty + 16 * i], s);
    }
  } else if (bid < 2048) {
    // ---- xtrans (two-pass): x -> x_t [b][c][m] bf16, xg_t [m][b][0..128)
    u16* t = (u16*)smem;                  // [128][68]
    int bx = bid - 1024;
    int b = bx >> 5;
    int m0 = (bx & 31) * 64;
    for (int it = 0; it < 32; ++it) {
      int idx = it * 256 + tid;
      int m = idx >> 7, c = idx & 127;
      float v = x[((size_t)b * NN + m0 + m) * CC + c];
      t[c * 68 + m] = f2bf(v);
    }
    __syncthreads();
    for (int it = 0; it < 32; ++it) {
      int idx = it * 256 + tid;
      int c = idx >> 6, m = idx & 63;
      x_t[((size_t)b * CC + c) * NN + m0 + m] = t[c * 68 + m];
    }
    for (int it = 0; it < 16; ++it) {
      int idx = it * 256 + tid;
      int m = idx >> 6, c2 = idx & 63;
      float2 v = *(const float2*)&x[((size_t)b * NN + m0 + m) * CC + c2 * 2];
      u32 pk = (u32)f2bf(v.x) | ((u32)f2bf(v.y) << 16);
      *(u32*)&xg_t[(((size_t)(m0 + m)) * 32 + b) * 256 + c2 * 2] = pk;
    }
  } else if (bid < 2304) {
    // ---- poolt: pool [d][ki][o] fp32 -> pool_r [(o,ki)][d] bf16
    float* t = (float*)smem;              // [128][65]
    int ki = bid - 2048;
    for (int it = 0; it < 32; ++it) {
      int idx = it * 256 + tid;
      int d = idx >> 7, o = idx & 127;
      t[o * 65 + d] = pool[d * 32768 + ki * 128 + o];
    }
    __syncthreads();
    for (int it = 0; it < 32; ++it) {
      int idx = it * 256 + tid;
      int o = idx >> 6, d = idx & 63;
      pool_r[((size_t)o * 256 + ki) * 64 + d] = f2bf(t[o * 65 + d]);
    }
  } else {
    // ---- prep: 4 nodes/block, one wave per node -> e_bf + biasb
    float* sh = (float*)smem;             // [4][64]
    int nw = tid >> 6, d = tid & 63;
    int n = (bid - 2304) * 4 + nw;
    float v = ne[n * EE + d] + te[d];
    float s = v;
#pragma unroll
    for (int off = 32; off > 0; off >>= 1) s += __shfl_xor(s, off);
    float mean = s * (1.0f / 64.0f);
    float c = v - mean;
    float q = c * c;
#pragma unroll
    for (int off = 32; off > 0; off >>= 1) q += __shfl_xor(q, off);
    float inv = rsqrtf(q * (1.0f / 64.0f) + 1e-12f);
    float ev = c * inv * lnw[d] + lnb[d];
    e_bf[n * EE + d] = f2bf(ev);
    sh[nw * 64 + d] = ev;
    __syncthreads();
#pragma unroll
    for (int oo = 0; oo < 2; ++oo) {
      int o = oo * 64 + d;
      float acc = 0.f;
#pragma unroll 8
      for (int dd = 0; dd < 64; ++dd) acc += sh[nw * 64 + dd] * bias_pool[dd * CC + o];
      bias_out[n * CC + o] = acc;
    }
  }
}

// ---------------- mega2: aggr(512 blocks, first) + gen(4096 blocks), block-ranged
// aggr: 2-phase dbuf (stage t+1 before compute t), 64KB LDS, 1 barrier/iter.
__global__ __launch_bounds__(256, 2) void k_mega2(
    const u16* __restrict__ P, const u16* __restrict__ x_t,
    const float* __restrict__ rs, u16* __restrict__ xg_t,
    const u16* __restrict__ e_bf, const u16* __restrict__ pool_r,
    u16* __restrict__ W_p) {
  __shared__ __align__(16) char smem[65536];
  int tid = threadIdx.x;
  int lane = tid & 63, w = tid >> 6;
  int lm = lane & 15, lq = lane >> 4;
  if (blockIdx.x < 512) {
    // ---- aggr: XOR-swizzled staging+reads, mb%8 XCD pin, double-buffered.
    int mb = blockIdx.x & 15, b = blockIdx.x >> 4;
    int n0 = mb * 128;
    int wm = w >> 1, wn = w & 1;
    f32x4 acc[4][4] = {};
    const u16* a_src = P + (size_t)n0 * NN;
    const u16* b_src = x_t + (size_t)b * CC * NN;
    auto STAGE = [&](int kc, char* buf) {
      u16* As = (u16*)buf;
      u16* Bs = (u16*)(buf + 16384);
#pragma unroll
      for (int ii = 0; ii < 4; ++ii) {
        int idx = ii * 256 + tid;
        int row = idx >> 3, ch = idx & 7;
        int sc = kc + ((ch ^ (row & 7)) << 3);   // pre-swizzled source col
        __builtin_amdgcn_global_load_lds((gas1)(a_src + (size_t)row * NN + sc),
                                         (las3)(As + (size_t)(ii * 256 + w * 64) * 8), 16, 0, 0);
        __builtin_amdgcn_global_load_lds((gas1)(b_src + (size_t)row * NN + sc),
                                         (las3)(Bs + (size_t)(ii * 256 + w * 64) * 8), 16, 0, 0);
      }
    };
    STAGE(0, smem);
    __syncthreads();
    for (int t = 0; t < 32; ++t) {
      if (t < 31) STAGE((t + 1) * 64, smem + (((t + 1) & 1) << 15));
      char* cur = smem + ((t & 1) << 15);
      u16* As = (u16*)cur;
      u16* Bs = (u16*)(cur + 16384);
#pragma unroll
      for (int kk = 0; kk < 64; kk += 32) {
        int cb = (kk >> 3) + lq;                 // 16B chunk index (unswizzled)
        bf16x8 af[4], bq[4];
#pragma unroll
        for (int i = 0; i < 4; ++i) {
          int row = wm * 64 + i * 16 + lm;
          af[i] = *(const bf16x8*)&As[row * 64 + ((cb ^ (row & 7)) << 3)];
        }
#pragma unroll
        for (int j = 0; j < 4; ++j) {
          int row = wn * 64 + j * 16 + lm;
          bq[j] = *(const bf16x8*)&Bs[row * 64 + ((cb ^ (row & 7)) << 3)];
        }
#pragma unroll
        for (int i = 0; i < 4; ++i)
#pragma unroll
          for (int j = 0; j < 4; ++j)
            acc[i][j] = mfma16(af[i], bq[j], acc[i][j]);
      }
      __syncthreads();
    }
#pragma unroll
    for (int i = 0; i < 4; ++i) {
      int nr = n0 + wm * 64 + i * 16 + lq * 4;
#pragma unroll
      for (int r = 0; r < 4; ++r) {
        float sc = 1.0f / rs[nr + r];
#pragma unroll
        for (int j = 0; j < 4; ++j) {
          int c = wn * 64 + j * 16 + lm;
          xg_t[((size_t)(nr + r) * 32 + b) * 256 + 128 + c] = f2bf(acc[i][j][r] * sc);
        }
      }
    }
  } else {
    // ---- gen v3: 2 o x 32 nodes x 256 ki; g = nb*64 + og -> XCD = og%8
    // (o-pin: 16 o = 512KB pool_r per XCD, L2-resident).
    // Store per (n,ks): [2o][32ki] = 128B full line.
    u16* Tl = (u16*)smem;
    int g = blockIdx.x - 512;
    int og = g & 63, nb = g >> 6;
    int o0 = og * 2, n0 = nb * 32;
    int o_l = w & 1, kih = w >> 1;
    bf16x8 eB[2][2];
#pragma unroll
    for (int nt = 0; nt < 2; ++nt)
#pragma unroll
      for (int ks = 0; ks < 2; ++ks)
        eB[nt][ks] = *(const bf16x8*)&e_bf[(n0 + nt * 16 + lm) * EE + ks * 32 + lq * 8];
    const u16* pbase = pool_r + ((size_t)(o0 + o_l) * 256 + kih * 128) * 64;
#pragma unroll
    for (int ct = 0; ct < 8; ++ct) {
      const u16* ap = pbase + (ct * 16 + lm) * 64 + lq * 8;
      bf16x8 pA0 = *(const bf16x8*)ap;          // d = lq*8..
      bf16x8 pA1 = *(const bf16x8*)(ap + 32);   // d = 32+lq*8..
#pragma unroll
      for (int nt = 0; nt < 2; ++nt) {
        f32x4 gv = {0.f, 0.f, 0.f, 0.f};
        gv = mfma16(pA0, eB[nt][0], gv);
        gv = mfma16(pA1, eB[nt][1], gv);
        // D: node = lm (col), ki = kih*128 + ct*16 + lq*4 + r (row)
        ushort4 h;
        h.x = f2bf(gv[0]); h.y = f2bf(gv[1]); h.z = f2bf(gv[2]); h.w = f2bf(gv[3]);
        *(ushort4*)&Tl[o_l * 8456 + (nt * 16 + lm) * 264 + kih * 128 + ct * 16 + lq * 4] = h;
      }
    }
    __syncthreads();
    // store: W_p[n][ks][o][ki%32]; per wave: one n, 8 ks-lines of 128B.
#pragma unroll
    for (int it = 0; it < 8; ++it) {
      int idx = it * 256 + tid;
      int n = idx >> 6, rem = idx & 63;
      int ks = rem >> 3, rem2 = rem & 7;
      int o = rem2 >> 2, ki8 = rem2 & 3;
      uint4 v = *(const uint4*)&Tl[o * 8456 + n * 264 + ks * 32 + ki8 * 8];
      *(uint4*)&W_p[(size_t)(n0 + n) * 32768 + ks * 4096 + (o0 + o) * 32 + ki8 * 8] = v;
    }
  }
}

// ---------------- k_apply v3: out[b,n,o] = xg[n] @ W[n] + bias.
// W_p permuted -> B-frag loads fully-coalesced 1KB/wave. Epilogue staged
// through LDS: out written as 64 rows x 512B contiguous float4 bursts.
__global__ __launch_bounds__(256, 3) void k_apply(const u16* __restrict__ xg_t,
                                                  const u16* __restrict__ W_p,
                                                  const float* __restrict__ bias,
                                                  float* __restrict__ out) {
  __shared__ float L[2 * 32 * 132];     // 33792 B
  int n0 = blockIdx.x * 2;
  int tid = threadIdx.x;
  int lane = tid & 63, w = tid >> 6;
  int lm = lane & 15, lq = lane >> 4;
  int n = n0 + (w & 1), oh = w >> 1;    // node, o-half(64)
  const u16* xb = xg_t + (size_t)n * 32 * 256;
  const u16* wb = W_p + (size_t)n * 32768 + (size_t)oh * 64 * 32;
  f32x4 acc[2][4] = {};
#pragma unroll
  for (int ks = 0; ks < 8; ++ks) {
    int ko = ks * 32 + lq * 8;
    bf16x8 a0 = *(const bf16x8*)&xb[lm * 256 + ko];
    bf16x8 a1 = *(const bf16x8*)&xb[(16 + lm) * 256 + ko];
#pragma unroll
    for (int ot = 0; ot < 4; ++ot) {
      bf16x8 bv = *(const bf16x8*)&wb[(size_t)ks * 4096 + (ot * 16 + lm) * 32 + lq * 8];
      acc[0][ot] = mfma16(a0, bv, acc[0][ot]);
      acc[1][ot] = mfma16(a1, bv, acc[1][ot]);
    }
  }
  // stage acc to LDS: L[nl][b][oc]
#pragma unroll
  for (int ot = 0; ot < 4; ++ot) {
    int oc = oh * 64 + ot * 16 + lm;
#pragma unroll
    for (int mt = 0; mt < 2; ++mt)
#pragma unroll
      for (int r = 0; r < 4; ++r) {
        int b = mt * 16 + lq * 4 + r;
        L[((w & 1) * 32 + b) * 132 + oc] = acc[mt][ot][r];
      }
  }
  __syncthreads();
  // write phase: 64 rows (2n x 32b) x 128 floats; 512B burst per row.
#pragma unroll
  for (int it = 0; it < 8; ++it) {
    int idx = it * 256 + tid;
    int row = idx >> 5, seg = idx & 31;
    int nl = row >> 5, b = row & 31;
    float4 v = *(const float4*)&L[(nl * 32 + b) * 132 + seg * 4];
    float4 bv = *(const float4*)&bias[(n0 + nl) * CC + seg * 4];
    float4 o4;
    o4.x = v.x + bv.x; o4.y = v.y + bv.y; o4.z = v.z + bv.z; o4.w = v.w + bv.w;
    *(float4*)&out[((size_t)b * NN + n0 + nl) * CC + seg * 4] = o4;
  }
}

extern "C" void kernel_launch(void* const* d_in, const int* in_sizes, int n_in,
                              void* d_out, int out_size, void* d_ws, size_t ws_size,
                              hipStream_t stream) {
  const float* x        = (const float*)d_in[0];
  const float* node_emb = (const float*)d_in[1];
  const float* time_emb = (const float*)d_in[2];
  const float* pool     = (const float*)d_in[3];
  const float* bias_pl  = (const float*)d_in[4];
  const float* ln_w     = (const float*)d_in[5];
  const float* ln_b     = (const float*)d_in[6];
  float* out = (float*)d_out;

  char* p = (char*)d_ws;
  auto alloc = [&](size_t bytes) {
    char* r = p;
    p += (bytes + 255) & ~(size_t)255;
    return r;
  };
  u16*   e_bf   = (u16*)  alloc((size_t)NN * EE * 2);
  float* biasb  = (float*)alloc((size_t)NN * CC * 4);
  u16*   Pm     = (u16*)  alloc((size_t)NN * NN * 2);          // exp(S), unnormalized
  float* rs     = (float*)alloc((size_t)NN * 4);               // row sums
  u16*   x_t    = (u16*)  alloc((size_t)BB * CC * NN * 2);
  u16*   xg_t   = (u16*)  alloc((size_t)NN * BB * 256 * 2);    // [node][batch][x||xagg]
  u16*   pool_r = (u16*)  alloc((size_t)128 * 256 * 64 * 2);
  u16*   W_p    = (u16*)  alloc((size_t)NN * 32768 * 2);       // 128 MB, permuted

  if (ws_size < (size_t)(p - (char*)d_ws)) return;

  (void)hipMemsetAsync(rs, 0, (size_t)NN * 4, stream);

  k_mega0<<<2816, 256, 0, stream>>>(x, node_emb, time_emb, pool, bias_pl, ln_w, ln_b,
                                    e_bf, biasb, pool_r, x_t, xg_t, Pm, rs);
  k_mega2<<<4608, 256, 0, stream>>>(Pm, x_t, rs, xg_t, e_bf, pool_r, W_p);
  k_apply<<<NN / 2, 256, 0, stream>>>(xg_t, W_p, biasb, out);
}